// Round 4
// baseline (10998.964 us; speedup 1.0000x reference)
//
#include <hip/hip_runtime.h>
#include <math.h>

#define Tn 1024
#define Bn 64
#define INn 512
#define Hn 1024
#define Mn (Tn*Bn)   // 65536

// ================= Kernel 1: xproj = x @ Wx + bias =================
// C[M][Hn] = A[M][INn] * W[INn][Hn] + bias, fp32, 128x128x16 tiles, 8x8 micro
#define BM 128
#define BN 128
#define BK 16

__global__ __launch_bounds__(256) void xproj_gemm(
    const float* __restrict__ A,    // [M][INn]
    const float* __restrict__ W,    // [INn][Hn]
    const float* __restrict__ bias, // [Hn]
    float* __restrict__ C)          // [M][Hn]
{
    __shared__ float As[BK][BM + 4];   // transposed: As[k][m]; row stride 132f = 33*16B (16B-aligned)
    __shared__ float Bs[BK][BN + 4];

    const int tid = threadIdx.x;
    const int n0 = blockIdx.x * BN;
    const int m0 = blockIdx.y * BM;
    const int tm = tid >> 4;       // 0..15
    const int tn = tid & 15;       // 0..15

    float acc[8][8];
    #pragma unroll
    for (int i = 0; i < 8; ++i)
        #pragma unroll
        for (int j = 0; j < 8; ++j) acc[i][j] = 0.f;

    for (int k0 = 0; k0 < INn; k0 += BK) {
        #pragma unroll
        for (int r = 0; r < 2; ++r) {
            int f = tid + 256 * r;
            int row = f >> 2;
            int c4 = (f & 3) * 4;
            const float4 v = *reinterpret_cast<const float4*>(
                &A[(size_t)(m0 + row) * INn + k0 + c4]);
            As[c4 + 0][row] = v.x;
            As[c4 + 1][row] = v.y;
            As[c4 + 2][row] = v.z;
            As[c4 + 3][row] = v.w;
        }
        #pragma unroll
        for (int r = 0; r < 2; ++r) {
            int f = tid + 256 * r;
            int kk = f >> 5;
            int n4 = (f & 31) * 4;
            *reinterpret_cast<float4*>(&Bs[kk][n4]) =
                *reinterpret_cast<const float4*>(
                    &W[(size_t)(k0 + kk) * Hn + n0 + n4]);
        }
        __syncthreads();

        #pragma unroll
        for (int k = 0; k < BK; ++k) {
            // vectorized fragment reads: 4x ds_read_b128 instead of 16x ds_read_b32
            const float4 a0 = *reinterpret_cast<const float4*>(&As[k][tm * 8]);
            const float4 a1 = *reinterpret_cast<const float4*>(&As[k][tm * 8 + 4]);
            const float4 b0 = *reinterpret_cast<const float4*>(&Bs[k][tn * 8]);
            const float4 b1 = *reinterpret_cast<const float4*>(&Bs[k][tn * 8 + 4]);
            const float a[8] = {a0.x, a0.y, a0.z, a0.w, a1.x, a1.y, a1.z, a1.w};
            const float bfr[8] = {b0.x, b0.y, b0.z, b0.w, b1.x, b1.y, b1.z, b1.w};
            #pragma unroll
            for (int i = 0; i < 8; ++i)
                #pragma unroll
                for (int j = 0; j < 8; ++j)
                    acc[i][j] = fmaf(a[i], bfr[j], acc[i][j]);
        }
        __syncthreads();
    }

    const float4 bv0 = *reinterpret_cast<const float4*>(&bias[n0 + tn * 8]);
    const float4 bv1 = *reinterpret_cast<const float4*>(&bias[n0 + tn * 8 + 4]);
    #pragma unroll
    for (int i = 0; i < 8; ++i) {
        const int m = m0 + tm * 8 + i;
        float4 o0, o1;
        o0.x = acc[i][0] + bv0.x; o0.y = acc[i][1] + bv0.y;
        o0.z = acc[i][2] + bv0.z; o0.w = acc[i][3] + bv0.w;
        o1.x = acc[i][4] + bv1.x; o1.y = acc[i][5] + bv1.y;
        o1.z = acc[i][6] + bv1.z; o1.w = acc[i][7] + bv1.w;
        *reinterpret_cast<float4*>(&C[(size_t)m * Hn + n0 + tn * 8]) = o0;
        *reinterpret_cast<float4*>(&C[(size_t)m * Hn + n0 + tn * 8 + 4]) = o1;
    }
}

// ================= Kernel 2: persistent recurrence scan =================
// 256 blocks (1/CU, forced by 136 KB LDS). Group g = blockIdx%8 owns b-rows
// [8g, 8g+8); its 32 member blocks j-partition H (32 cols each) and barrier
// only among themselves (batch rows are independent recurrences). blockIdx%8
// also makes each group XCD-local under round-robin dispatch (perf hint only).
// Block: 512 thr = 8 waves; wave ks owns k-slice [128*ks,128*ks+128).
// Thread (ks, b, j4) accumulates 4 outputs (b, j0+4*j4..+3) over its k-slice;
// cross-ks reduce via LDS; wave 0 applies xp + tanh and stores h_t.
// Wh 32-col slice pinned in LDS [1024][32] (one-time load; reads are 8
// distinct 16B addrs/wave, 8-way b-broadcast -> minimum LDS traffic).
__global__ __launch_bounds__(512, 2) void rnn_scan(
    const float* __restrict__ h0,   // [Bn][Hn]
    const float* __restrict__ Whp,  // [Hn][Hn]
    float* __restrict__ out,        // [Tn][Bn][Hn]: xproj in, h_t out (in place)
    unsigned int* __restrict__ bar) // 8 counters, 256B apart, pre-zeroed
{
    extern __shared__ float lds[];
    float*  wh  = lds;                                        // [1024][32] = 128 KB
    float4* red = reinterpret_cast<float4*>(lds + 1024 * 32); // [512] = 8 KB

    const int tid  = threadIdx.x;
    const int grp  = blockIdx.x & 7;
    const int jb   = blockIdx.x >> 3;
    const int j0   = jb * 32;
    const int b0   = grp * 8;
    const int ks   = tid >> 6;      // wave id = k-slice 0..7
    const int lane = tid & 63;
    const int b    = lane >> 3;     // 0..7
    const int j4   = lane & 7;      // 0..7 (4 cols each)
    const int k0   = ks * 128;

    // one-time Wh slice stage: wh[k][j] = Whp[k][j0+j]
    for (int idx = tid; idx < 8192; idx += 512) {
        int k = idx >> 3, q = idx & 7;
        *reinterpret_cast<float4*>(&wh[k * 32 + q * 4]) =
            *reinterpret_cast<const float4*>(&Whp[(size_t)k * Hn + j0 + q * 4]);
    }
    __syncthreads();

    unsigned int* cnt = bar + (size_t)grp * 64;
    const size_t rowstride = (size_t)Bn * Hn;
    int budget = 1 << 24;   // spin bailout: wrong-answer beats a hang

    #pragma clang loop unroll(disable)
    for (int t = 0; t < Tn; ++t) {
        const float* hp = (t == 0)
            ? (h0 + (size_t)(b0 + b) * Hn)
            : (out + (size_t)(t - 1) * rowstride + (size_t)(b0 + b) * Hn);

        float4 acc = make_float4(0.f, 0.f, 0.f, 0.f);
        float4 hbuf[8];
        #pragma unroll
        for (int p = 0; p < 8; ++p)
            hbuf[p] = *reinterpret_cast<const float4*>(&hp[k0 + p * 4]);

        #pragma unroll
        for (int it = 0; it < 4; ++it) {
            float4 cur[8];
            #pragma unroll
            for (int p = 0; p < 8; ++p) cur[p] = hbuf[p];
            if (it < 3) {   // prefetch next 32 k (hides ~200cy L2 latency)
                #pragma unroll
                for (int p = 0; p < 8; ++p)
                    hbuf[p] = *reinterpret_cast<const float4*>(
                        &hp[k0 + (it + 1) * 32 + p * 4]);
            }
            const int kb = k0 + it * 32;
            #pragma unroll
            for (int p = 0; p < 8; ++p) {
                const int k = kb + p * 4;
                const float4 hv = cur[p];
                const float4 w0 = *reinterpret_cast<const float4*>(&wh[(k + 0) * 32 + j4 * 4]);
                const float4 w1 = *reinterpret_cast<const float4*>(&wh[(k + 1) * 32 + j4 * 4]);
                const float4 w2 = *reinterpret_cast<const float4*>(&wh[(k + 2) * 32 + j4 * 4]);
                const float4 w3 = *reinterpret_cast<const float4*>(&wh[(k + 3) * 32 + j4 * 4]);
                acc.x = fmaf(hv.x, w0.x, acc.x); acc.y = fmaf(hv.x, w0.y, acc.y);
                acc.z = fmaf(hv.x, w0.z, acc.z); acc.w = fmaf(hv.x, w0.w, acc.w);
                acc.x = fmaf(hv.y, w1.x, acc.x); acc.y = fmaf(hv.y, w1.y, acc.y);
                acc.z = fmaf(hv.y, w1.z, acc.z); acc.w = fmaf(hv.y, w1.w, acc.w);
                acc.x = fmaf(hv.z, w2.x, acc.x); acc.y = fmaf(hv.z, w2.y, acc.y);
                acc.z = fmaf(hv.z, w2.z, acc.z); acc.w = fmaf(hv.z, w2.w, acc.w);
                acc.x = fmaf(hv.w, w3.x, acc.x); acc.y = fmaf(hv.w, w3.y, acc.y);
                acc.z = fmaf(hv.w, w3.z, acc.z); acc.w = fmaf(hv.w, w3.w, acc.w);
            }
        }

        red[tid] = acc;
        __syncthreads();

        if (tid < 64) {   // wave 0: reduce 8 partials, add xp, tanh, store
            float4 s = red[lane];
            #pragma unroll
            for (int q = 1; q < 8; ++q) {
                float4 r = red[q * 64 + lane];
                s.x += r.x; s.y += r.y; s.z += r.z; s.w += r.w;
            }
            float* orow = out + (size_t)t * rowstride
                              + (size_t)(b0 + b) * Hn + j0 + j4 * 4;
            const float4 xp = *reinterpret_cast<const float4*>(orow);
            float4 hn;
            hn.x = tanhf(xp.x + s.x);
            hn.y = tanhf(xp.y + s.y);
            hn.z = tanhf(xp.z + s.z);
            hn.w = tanhf(xp.w + s.w);
            *reinterpret_cast<float4*>(orow) = hn;
        }
        __syncthreads();   // drains wave0's stores before the group barrier

        if (tid == 0) {    // group barrier: monotonic counter, agent scope
            __hip_atomic_fetch_add(cnt, 1u, __ATOMIC_RELEASE,
                                   __HIP_MEMORY_SCOPE_AGENT);
            const unsigned int target = 32u * (unsigned int)(t + 1);
            while (__hip_atomic_load(cnt, __ATOMIC_RELAXED,
                                     __HIP_MEMORY_SCOPE_AGENT) < target
                   && budget > 0) {
                __builtin_amdgcn_s_sleep(1);
                --budget;
            }
            // acquire-ordered load = cache-invalidate before next step's reads
            (void)__hip_atomic_load(cnt, __ATOMIC_ACQUIRE,
                                    __HIP_MEMORY_SCOPE_AGENT);
        }
        __syncthreads();
    }
}

extern "C" void kernel_launch(void* const* d_in, const int* in_sizes, int n_in,
                              void* d_out, int out_size, void* d_ws, size_t ws_size,
                              hipStream_t stream) {
    const float* x  = (const float*)d_in[0];   // [T][B][IN]
    const float* h0 = (const float*)d_in[1];   // [B][H]
    const float* W  = (const float*)d_in[2];   // [IN+H][H]
    const float* bi = (const float*)d_in[3];   // [H]
    float* out = (float*)d_out;                // [T][B][H]

    const float* Wx = W;
    const float* Wh = W + (size_t)INn * Hn;

    // zero the 8 barrier counters (d_ws is poisoned 0xAA before every call)
    (void)hipMemsetAsync(d_ws, 0, 8 * 64 * sizeof(unsigned int), stream);

    // 1) xproj for all timesteps, directly into out
    dim3 g1(Hn / BN, Mn / BM);   // (8, 512)
    xproj_gemm<<<g1, 256, 0, stream>>>(x, Wx, bi, out);

    // 2) persistent scan: 256 blocks, 136 KB dynamic LDS (>64KB needs attr)
    static const size_t scan_lds = (size_t)(1024 * 32 + 512 * 4) * sizeof(float);
    (void)hipFuncSetAttribute(reinterpret_cast<const void*>(rnn_scan),
                              hipFuncAttributeMaxDynamicSharedMemorySize,
                              (int)scan_lds);
    rnn_scan<<<256, 512, scan_lds, stream>>>(h0, Wh, out,
                                             (unsigned int*)d_ws);
}